// Round 1
// baseline (32.763 us; speedup 1.0000x reference)
//
#include <hip/hip_runtime.h>
#include <hip/hip_bf16.h>

#define NB 16       // batch
#define NS 256      // tokens per row
#define ND 512      // feature dim
#define MAXDUR 10
#define TMAX (NS * MAXDUR)   // 2560
#define ND4 (ND / 4)         // 128 float4 per row

// ---------------------------------------------------------------------------
// Kernel 1: per-batch inclusive scan of durations.
// grid = NB blocks, block = NS threads.
// Writes cum[B][S] and mel[B] (int) to workspace, mel_len (float) to d_out tail.
// ---------------------------------------------------------------------------
__global__ void la_scan_kernel(const int* __restrict__ dur,
                               int* __restrict__ cum,
                               int* __restrict__ mel,
                               float* __restrict__ mel_out) {
    __shared__ int s[NS];
    const int b = blockIdx.x;
    const int tid = threadIdx.x;

    s[tid] = dur[b * NS + tid];
    __syncthreads();

    // Hillis-Steele inclusive scan over NS=256 elements
    #pragma unroll
    for (int off = 1; off < NS; off <<= 1) {
        int t = (tid >= off) ? s[tid - off] : 0;
        __syncthreads();
        s[tid] += t;
        __syncthreads();
    }

    cum[b * NS + tid] = s[tid];
    if (tid == 0) {
        int m = s[NS - 1];
        mel[b] = m;
        mel_out[b] = (float)m;   // second tuple output, stored as float32
    }
}

// ---------------------------------------------------------------------------
// Kernel 2: per-batch searchsorted: idx[b][t] = min(first i with cum[i] > t, S-1)
// grid = NB blocks, block = NS threads; each thread handles MAXDUR frames.
// ---------------------------------------------------------------------------
__global__ void la_idx_kernel(const int* __restrict__ cum,
                              int* __restrict__ idx) {
    __shared__ int s[NS];
    const int b = blockIdx.x;
    const int tid = threadIdx.x;

    s[tid] = cum[b * NS + tid];
    __syncthreads();

    #pragma unroll
    for (int k = 0; k < MAXDUR; ++k) {
        int t = tid + k * NS;
        int lo = 0, hi = NS;
        while (lo < hi) {
            int mid = (lo + hi) >> 1;
            if (s[mid] > t) hi = mid; else lo = mid + 1;
        }
        int i = (lo < NS) ? lo : (NS - 1);
        idx[b * TMAX + t] = i;   // coalesced per k
    }
}

// ---------------------------------------------------------------------------
// Kernel 3: expand-gather. One float4 per thread, grid-stride.
// out[b,t,:] = (t < mel[b]) ? x[b, idx[b,t], :] : 0
// If idx == nullptr (ws too small), binary-search cum in-kernel instead.
// ---------------------------------------------------------------------------
__global__ void la_gather_kernel(const float4* __restrict__ x,
                                 const int* __restrict__ cum,
                                 const int* __restrict__ idx,
                                 const int* __restrict__ mel,
                                 float4* __restrict__ out) {
    const int total = NB * TMAX * ND4;          // 5,242,880
    for (int i = blockIdx.x * blockDim.x + threadIdx.x; i < total;
         i += gridDim.x * blockDim.x) {
        int b   = i / (TMAX * ND4);
        int rem = i - b * (TMAX * ND4);
        int t   = rem / ND4;
        int d4  = rem - t * ND4;

        float4 v = make_float4(0.f, 0.f, 0.f, 0.f);
        if (t < mel[b]) {
            int src;
            if (idx) {
                src = idx[b * TMAX + t];        // broadcast across 128 lanes
            } else {
                const int* c = cum + b * NS;
                int lo = 0, hi = NS;
                while (lo < hi) {
                    int mid = (lo + hi) >> 1;
                    if (c[mid] > t) hi = mid; else lo = mid + 1;
                }
                src = (lo < NS) ? lo : (NS - 1);
            }
            v = x[(b * NS + src) * ND4 + d4];
        }
        out[i] = v;
    }
}

extern "C" void kernel_launch(void* const* d_in, const int* in_sizes, int n_in,
                              void* d_out, int out_size, void* d_ws, size_t ws_size,
                              hipStream_t stream) {
    const float* x   = (const float*)d_in[0];
    const int*   dur = (const int*)d_in[1];

    float* out     = (float*)d_out;
    float* mel_out = out + (size_t)NB * TMAX * ND;   // tuple output 1 tail

    // workspace layout: cum[B*S] int | mel[B] int | idx[B*TMAX] int (optional)
    int* cum = (int*)d_ws;
    int* mel = cum + NB * NS;
    int* idx = mel + NB;
    const size_t need_base = (size_t)(NB * NS + NB) * sizeof(int);
    const size_t need_idx  = need_base + (size_t)NB * TMAX * sizeof(int);
    const bool use_idx = (ws_size >= need_idx);

    la_scan_kernel<<<NB, NS, 0, stream>>>(dur, cum, mel, mel_out);
    if (use_idx) {
        la_idx_kernel<<<NB, NS, 0, stream>>>(cum, idx);
    }
    la_gather_kernel<<<2048, 256, 0, stream>>>(
        (const float4*)x, cum, use_idx ? idx : nullptr, mel, (float4*)d_out);
}

// Round 2
// 28.757 us; speedup vs baseline: 1.1393x; 1.1393x over previous
//
#include <hip/hip_runtime.h>
#include <hip/hip_bf16.h>

#define NB 16       // batch
#define NS 256      // tokens per row
#define ND 512      // feature dim
#define MAXDUR 10
#define TMAX (NS * MAXDUR)   // 2560
#define ND4 (ND / 4)         // 128 float4 per row

// ---------------------------------------------------------------------------
// Kernel 1 (fused): per-batch inclusive scan of durations + searchsorted.
// grid = NB blocks, block = NS threads.
// Writes mel[B] (int) to ws, mel_len (float) to d_out tail, idx[B][TMAX] to ws.
// ---------------------------------------------------------------------------
__global__ void la_prep_kernel(const int* __restrict__ dur,
                               int* __restrict__ mel,
                               float* __restrict__ mel_out,
                               int* __restrict__ idx) {
    __shared__ int s[NS];
    const int b = blockIdx.x;
    const int tid = threadIdx.x;

    s[tid] = dur[b * NS + tid];
    __syncthreads();

    // Hillis-Steele inclusive scan over NS=256 elements
    #pragma unroll
    for (int off = 1; off < NS; off <<= 1) {
        int t = (tid >= off) ? s[tid - off] : 0;
        __syncthreads();
        s[tid] += t;
        __syncthreads();
    }

    if (tid == 0) {
        int m = s[NS - 1];
        mel[b] = m;
        mel_out[b] = (float)m;   // second tuple output, stored as float32
    }

    // searchsorted: idx[b][t] = min(first i with s[i] > t, S-1)
    #pragma unroll
    for (int k = 0; k < MAXDUR; ++k) {
        int t = tid + k * NS;
        int lo = 0, hi = NS;
        while (lo < hi) {
            int mid = (lo + hi) >> 1;
            if (s[mid] > t) hi = mid; else lo = mid + 1;
        }
        int i = (lo < NS) ? lo : (NS - 1);
        idx[b * TMAX + t] = i;   // coalesced per k
    }
}

// ---------------------------------------------------------------------------
// Kernel 2: expand-gather. One float4 per thread, no loops, no divisions.
// grid = (TMAX*ND4/256, NB) = (1280, 16), block = 256.
// out[b,t,:] = (t < mel[b]) ? x[b, idx[b,t], :] : 0
// ---------------------------------------------------------------------------
__global__ void la_gather_kernel(const float4* __restrict__ x,
                                 const int* __restrict__ idx,
                                 const int* __restrict__ mel,
                                 float4* __restrict__ out) {
    const int b   = blockIdx.y;
    const int rem = blockIdx.x * 256 + threadIdx.x;   // [0, TMAX*ND4)
    const int t   = rem >> 7;                          // / ND4
    const int d4  = rem & (ND4 - 1);

    float4 v = make_float4(0.f, 0.f, 0.f, 0.f);
    if (t < mel[b]) {                                  // wave-uniform branch
        int src = idx[b * TMAX + t];                   // broadcast across lanes
        v = x[(b * NS + src) * ND4 + d4];
    }
    out[(size_t)b * (TMAX * ND4) + rem] = v;
}

extern "C" void kernel_launch(void* const* d_in, const int* in_sizes, int n_in,
                              void* d_out, int out_size, void* d_ws, size_t ws_size,
                              hipStream_t stream) {
    const float* x   = (const float*)d_in[0];
    const int*   dur = (const int*)d_in[1];

    float* out     = (float*)d_out;
    float* mel_out = out + (size_t)NB * TMAX * ND;   // tuple output 1 tail

    // workspace layout: mel[B] int | idx[B*TMAX] int
    int* mel = (int*)d_ws;
    int* idx = mel + NB;

    la_prep_kernel<<<NB, NS, 0, stream>>>(dur, mel, mel_out, idx);
    la_gather_kernel<<<dim3(TMAX * ND4 / 256, NB), 256, 0, stream>>>(
        (const float4*)x, idx, mel, (float4*)d_out);
}

// Round 3
// 19.536 us; speedup vs baseline: 1.6771x; 1.4720x over previous
//
#include <hip/hip_runtime.h>
#include <hip/hip_bf16.h>

#define NB 16       // batch
#define NS 256      // tokens per row
#define ND 512      // feature dim
#define MAXDUR 10
#define TMAX (NS * MAXDUR)   // 2560
#define ND4 (ND / 4)         // 128 float4 per row
#define TB 32                // t-values per block
#define ITERS (TB * ND4 / 256)  // 16 float4 stores per thread

// ---------------------------------------------------------------------------
// Single fused kernel. grid = (TMAX/TB, NB) = (80, 16), block = 256.
// Each block: load its row's durations, wave-shfl inclusive scan (LDS combine),
// binary-search its TB output frames, then stream TB*ND floats of output.
// out[b,t,:] = (t < mel[b]) ? x[b, idx[b,t], :] : 0 ; mel_out[b] = mel (float)
// ---------------------------------------------------------------------------
__global__ __launch_bounds__(256) void la_fused_kernel(
    const float4* __restrict__ x,
    const int* __restrict__ dur,
    float4* __restrict__ out,
    float* __restrict__ mel_out) {
    __shared__ int s[NS];
    __shared__ int wsum[4];
    __shared__ int idx_s[TB];

    const int b    = blockIdx.y;
    const int tid  = threadIdx.x;
    const int lane = tid & 63;
    const int wid  = tid >> 6;

    // --- inclusive scan of durations (wave shfl + cross-wave LDS combine) ---
    int acc = dur[b * NS + tid];
    #pragma unroll
    for (int off = 1; off < 64; off <<= 1) {
        int n = __shfl_up(acc, off, 64);
        if (lane >= off) acc += n;
    }
    if (lane == 63) wsum[wid] = acc;
    __syncthreads();
    int add = 0;
    #pragma unroll
    for (int w = 0; w < 4; ++w)
        if (w < wid) add += wsum[w];
    acc += add;
    s[tid] = acc;
    __syncthreads();

    const int mel = s[NS - 1];
    if (blockIdx.x == 0 && tid == 0)
        mel_out[b] = (float)mel;    // second tuple output (float32)

    // --- searchsorted for this block's TB frames ---
    const int t0 = blockIdx.x * TB;
    if (tid < TB) {
        int t = t0 + tid;
        int lo = 0, hi = NS;
        while (lo < hi) {
            int mid = (lo + hi) >> 1;
            if (s[mid] > t) hi = mid; else lo = mid + 1;
        }
        idx_s[tid] = (lo < NS) ? lo : (NS - 1);
    }
    __syncthreads();

    // --- expand-gather: ITERS coalesced float4 stores per thread ---
    const size_t outbase = ((size_t)b * TMAX + t0) * ND4;
    const size_t xbase   = (size_t)b * NS * ND4;
    #pragma unroll
    for (int k = 0; k < ITERS; ++k) {
        int item = k * 256 + tid;
        int tt   = item >> 7;            // local t in [0, TB)  (wave-uniform)
        int d4   = item & (ND4 - 1);
        float4 v = make_float4(0.f, 0.f, 0.f, 0.f);
        if (t0 + tt < mel) {
            int src = idx_s[tt];         // LDS broadcast
            v = x[xbase + (size_t)src * ND4 + d4];
        }
        out[outbase + item] = v;
    }
}

extern "C" void kernel_launch(void* const* d_in, const int* in_sizes, int n_in,
                              void* d_out, int out_size, void* d_ws, size_t ws_size,
                              hipStream_t stream) {
    const float* x   = (const float*)d_in[0];
    const int*   dur = (const int*)d_in[1];

    float* out     = (float*)d_out;
    float* mel_out = out + (size_t)NB * TMAX * ND;   // tuple output 1 tail

    la_fused_kernel<<<dim3(TMAX / TB, NB), 256, 0, stream>>>(
        (const float4*)x, dur, (float4*)d_out, mel_out);
}